// Round 13
// baseline (93.121 us; speedup 1.0000x reference)
//
#include <hip/hip_runtime.h>
#include <hip/hip_bf16.h>
#include <math.h>

#define HW 16384          // 128*128
#define IMG 128
#define C_IN 128
#define C_OUT 64
#define NB 8
#define NE 4

typedef __attribute__((ext_vector_type(8))) short bf16x8;
typedef __attribute__((ext_vector_type(4))) float f32x4;

static __device__ __forceinline__ float bf2f_u(unsigned hbits) {
  union { unsigned u; float f; } v; v.u = hbits << 16;
  return v.f;
}
static __device__ __forceinline__ float bf2f_hi(unsigned w) {
  union { unsigned u; float f; } v; v.u = w & 0xFFFF0000u;
  return v.f;
}
// HW packed conversion: two f32 -> one u32 of 2 bf16 (v_cvt_pk_bf16_f32)
static __device__ __forceinline__ unsigned cvtpk(float a, float b) {
  __hip_bfloat162 p = __float22bfloat162_rn(make_float2(a, b));
  union { __hip_bfloat162 h; unsigned u; } v; v.h = p;
  return v.u;
}
// Dekker split of a float pair
static __device__ __forceinline__ void pk2(float a, float b,
                                           unsigned& hi, unsigned& lo) {
  hi = cvtpk(a, b);
  float ra = a - bf2f_u(hi & 0xFFFFu);
  float rb = b - bf2f_u(hi >> 16);
  lo = cvtpk(ra, rb);
}

union FragU { unsigned u[4]; uint4 q; bf16x8 v; };

#define ASYNC_LOAD16(gsrc, ldst)                                              \
  __builtin_amdgcn_global_load_lds(                                           \
      (const __attribute__((address_space(1))) void*)(gsrc),                  \
      (__attribute__((address_space(3))) void*)(ldst), 16, 0, 0)

// ---- K1: pre-fuse 1x1 conv as MFMA GEMM, async-DMA X staging, inline W ----
__global__ __launch_bounds__(64, 4) void prefuse_mfma(
    const float* __restrict__ x, const float* __restrict__ pre_w,
    const float* __restrict__ pre_b, unsigned short* __restrict__ x1,
    float* __restrict__ pmax, float* __restrict__ psum) {
  __shared__ float xls[2][1024];            // 2 x 4KB k-step buffers
  __shared__ unsigned short tbuf[16][72];   // transpose buffer
  int lane = threadIdx.x;
  int rowb = lane & 15;                     // A-row(px) / B-col(o)
  int kg = lane >> 4;                       // k-group 0..3
  int blk = blockIdx.x;                     // 4096
  int b = blk >> 9;
  int strip = blk & 511;
  int px0 = strip << 5;                     // 32 px per strip

  const float* xbase = x + (size_t)b * C_IN * HW + px0;

#define STAGE(ks, bf)                                                         \
  {                                                                           \
    _Pragma("unroll")                                                         \
    for (int r = 0; r < 4; ++r) {                                             \
      int ch = (ks) * 32 + r * 8 + (lane >> 3);                               \
      int qs = (lane & 7) ^ ((r * 2 + (lane >> 5)) & 7);                      \
      ASYNC_LOAD16(xbase + (size_t)ch * HW + qs * 4, &xls[bf][r * 256]);      \
    }                                                                         \
  }

  STAGE(0, 0)

  f32x4 acc[2][4];                          // [px-tile][o-tile]
#pragma unroll
  for (int ot = 0; ot < 4; ++ot) {
    float t = pre_b[ot * 16 + rowb];
#pragma unroll
    for (int pt = 0; pt < 2; ++pt) acc[pt][ot] = (f32x4){t, t, t, t};
  }

#pragma unroll
  for (int k = 0; k < 4; ++k) {
    // inline W-frag pack for this k-step (block-redundant, measured free)
    FragU wh[4], wl[4];
#pragma unroll
    for (int ot = 0; ot < 4; ++ot) {
      const float* wp = pre_w + (ot * 16 + rowb) * C_IN + k * 32 + kg * 8;
      float4 a = *(const float4*)wp;
      float4 cq = *(const float4*)(wp + 4);
      pk2(a.x, a.y, wh[ot].u[0], wl[ot].u[0]);
      pk2(a.z, a.w, wh[ot].u[1], wl[ot].u[1]);
      pk2(cq.x, cq.y, wh[ot].u[2], wl[ot].u[2]);
      pk2(cq.z, cq.w, wh[ot].u[3], wl[ot].u[3]);
    }
    if (k < 3) {
      STAGE(k + 1, (k + 1) & 1)
      asm volatile("s_waitcnt vmcnt(4)" ::: "memory");  // buf k done; k+1 in flight
    } else {
      asm volatile("s_waitcnt vmcnt(0)" ::: "memory");
    }
    const float* xb = xls[k & 1];
#pragma unroll
    for (int pt = 0; pt < 2; ++pt) {
      float xv[8];
#pragma unroll
      for (int j = 0; j < 8; ++j) {
        int ch = kg * 8 + j;
        int qq = ((pt * 4 + (rowb >> 2)) ^ (ch >> 2)) & 7;
        xv[j] = xb[ch * 32 + qq * 4 + (rowb & 3)];
      }
      FragU h, l;
      pk2(xv[0], xv[1], h.u[0], l.u[0]);
      pk2(xv[2], xv[3], h.u[1], l.u[1]);
      pk2(xv[4], xv[5], h.u[2], l.u[2]);
      pk2(xv[6], xv[7], h.u[3], l.u[3]);
#pragma unroll
      for (int ot = 0; ot < 4; ++ot) {
        acc[pt][ot] = __builtin_amdgcn_mfma_f32_16x16x32_bf16(h.v, wh[ot].v, acc[pt][ot], 0, 0, 0);
        acc[pt][ot] = __builtin_amdgcn_mfma_f32_16x16x32_bf16(l.v, wh[ot].v, acc[pt][ot], 0, 0, 0);
        acc[pt][ot] = __builtin_amdgcn_mfma_f32_16x16x32_bf16(h.v, wl[ot].v, acc[pt][ot], 0, 0, 0);
      }
    }
  }
#undef STAGE

  // epilogue: pooling partials + LDS transpose -> bf16 x1 store
#pragma unroll
  for (int ot = 0; ot < 4; ++ot) {
    float m = -INFINITY, s = 0.f;
#pragma unroll
    for (int pt = 0; pt < 2; ++pt)
#pragma unroll
      for (int r = 0; r < 4; ++r) {
        float v = acc[pt][ot][r];
        m = fmaxf(m, v); s += v;
      }
    m = fmaxf(m, __shfl_xor(m, 16)); s += __shfl_xor(s, 16);
    m = fmaxf(m, __shfl_xor(m, 32)); s += __shfl_xor(s, 32);
    if (lane < 16) {
      int idx = strip * 512 + b * 64 + ot * 16 + lane;  // [strip][bo]
      pmax[idx] = m; psum[idx] = s;
    }
    // D: row(px) = pt*16 + kg*4 + r, col(o) = rowb
#pragma unroll
    for (int pt = 0; pt < 2; ++pt) {
      uint2 p;
      p.x = cvtpk(acc[pt][ot][0], acc[pt][ot][1]);
      p.y = cvtpk(acc[pt][ot][2], acc[pt][ot][3]);
      *(uint2*)&tbuf[rowb][pt * 16 + kg * 4] = p;
    }
    __syncthreads();  // 1-wave block: cheap ordering fence
    uint4 val = *(const uint4*)&tbuf[lane >> 2][(lane & 3) * 8];
    unsigned short* op = x1 + ((size_t)b * C_OUT + ot * 16 + (lane >> 2)) * HW
                            + px0 + (lane & 3) * 8;
    *(uint4*)op = val;
    __syncthreads();  // WAR guard before next ot reuses tbuf
  }
}

// ---- K2: pooling finish + gate, one block per batch ----
__global__ __launch_bounds__(256) void pool_gate_kernel(
    const float* __restrict__ pmax, const float* __restrict__ psum,
    const float* __restrict__ gw0, const float* __restrict__ gb0,
    const float* __restrict__ gw1, const float* __restrict__ gb1,
    float* __restrict__ cof) {
  __shared__ float red_m[256], red_s[256];
  __shared__ float pooled[C_OUT];
  __shared__ float dd[8];
  int b = blockIdx.x;            // 0..7
  int t = threadIdx.x;
  int o = t & 63, chunk = t >> 6;
  float m = -INFINITY, s = 0.f;
  for (int st = chunk * 128; st < chunk * 128 + 128; ++st) {
    m = fmaxf(m, pmax[st * 512 + b * 64 + o]);
    s += psum[st * 512 + b * 64 + o];
  }
  red_m[t] = m; red_s[t] = s;
  __syncthreads();
  if (t < 64) {
    m = fmaxf(fmaxf(red_m[t], red_m[t + 64]), fmaxf(red_m[t + 128], red_m[t + 192]));
    s = ((red_s[t] + red_s[t + 64]) + (red_s[t + 128] + red_s[t + 192]));
    pooled[t] = m + s * (1.0f / HW);
  }
  __syncthreads();
  if (t < NE) {
    float d0 = gb0[t], d1 = gb1[t];
    for (int k = 0; k < C_OUT; ++k) {
      float pv = pooled[k];
      d0 = fmaf(pv, gw0[t * C_OUT + k], d0);
      d1 = fmaf(pv, gw1[t * C_OUT + k], d1);
    }
    dd[t] = d0; dd[4 + t] = d1;
  }
  __syncthreads();
  if (t == 0) {
    float logits[NE], noise[NE];
#pragma unroll
    for (int e = 0; e < NE; ++e) {
      float d1 = dd[4 + e];
      logits[e] = d1 > 0.f ? d1 : 0.2f * d1;
      noise[e] = log1pf(expf(dd[e]));
    }
    float mn = 0.25f * (noise[0] + noise[1] + noise[2] + noise[3]);
    float var = 0.f;
#pragma unroll
    for (int e = 0; e < NE; ++e) { float d = noise[e] - mn; var += d * d; }
    float sd = sqrtf(var * (1.0f / 3.0f));
    float scores[NE];
#pragma unroll
    for (int e = 0; e < NE; ++e) scores[e] = logits[e] + (noise[e] - mn) / sd;
    int i0 = 0;
#pragma unroll
    for (int e = 1; e < NE; ++e) if (scores[e] > scores[i0]) i0 = e;
    int i1 = -1;
#pragma unroll
    for (int e = 0; e < NE; ++e)
      if (e != i0 && (i1 < 0 || scores[e] > scores[i1])) i1 = e;
    float mm = fmaxf(logits[i0], logits[i1]);
    float e0 = expf(logits[i0] - mm), e1 = expf(logits[i1] - mm);
    float inv = 1.0f / (e0 + e1);
#pragma unroll
    for (int e = 0; e < NE; ++e) cof[b * NE + e] = 0.f;
    cof[b * NE + i0] = e0 * inv;
    cof[b * NE + i1] = e1 * inv;
  }
}

// ---- K3: fused experts v2 — register-resident h, no hs LDS ----
// tile = 32 rows x 128 cols per (b,c); 256 threads, thread = 4x4 out patch.
__global__ __launch_bounds__(256) void expert_kernel(
    const unsigned short* __restrict__ x1, const float* __restrict__ ew1,
    const float* __restrict__ eb1, const float* __restrict__ ew2,
    const float* __restrict__ eb2, const float* __restrict__ cof,
    float* __restrict__ out) {
  __shared__ float xs[36][136];   // image col gx at 4+gx; halo cols 2,3,132,133
  int tid = threadIdx.x, blk = blockIdx.x;
  int rt = blk & 3;               // row tile 0..3
  int c = (blk >> 2) & 63;
  int b = blk >> 8;
  int ty0 = rt * 32;
  const unsigned short* xp = x1 + ((size_t)b * C_OUT + c) * HW;

  // the two active experts (uniform per block)
  int eA = -1, eB = -1; float cfA = 0.f, cfB = 0.f;
#pragma unroll
  for (int e = 0; e < NE; ++e) {
    float cv = cof[b * NE + e];
    if (cv != 0.f) { if (eA < 0) { eA = e; cfA = cv; } else { eB = e; cfB = cv; } }
  }
  if (eA < 0) { eA = 0; cfA = 0.f; }
  if (eB < 0) { eB = eA; cfB = 0.f; }

  float w1A[9], w1B[9], w2A[9], w2B[9];
#pragma unroll
  for (int t = 0; t < 9; ++t) {
    w1A[t] = ew1[((size_t)eA * C_OUT + c) * 9 + t];
    w1B[t] = ew1[((size_t)eB * C_OUT + c) * 9 + t];
    w2A[t] = cfA * ew2[((size_t)eA * C_OUT + c) * 9 + t];
    w2B[t] = cfB * ew2[((size_t)eB * C_OUT + c) * 9 + t];
  }
  float b1A = eb1[eA * C_OUT + c], b1B = eb1[eB * C_OUT + c];
  float bias2 = cfA * eb2[eA * C_OUT + c] + cfB * eb2[eB * C_OUT + c];

  // stage 36 rows x 128 cols (bf16 -> fp32), zeros outside image
  for (int i = tid; i < 36 * 16; i += 256) {
    int r = i >> 4, seg = i & 15;
    int gy = ty0 - 2 + r;
    float4 f0 = make_float4(0.f, 0.f, 0.f, 0.f), f1 = f0;
    if ((unsigned)gy < 128u) {
      uint4 u = *(const uint4*)(xp + gy * IMG + seg * 8);
      f0.x = bf2f_u(u.x); f0.y = bf2f_hi(u.x);
      f0.z = bf2f_u(u.y); f0.w = bf2f_hi(u.y);
      f1.x = bf2f_u(u.z); f1.y = bf2f_hi(u.z);
      f1.z = bf2f_u(u.w); f1.w = bf2f_hi(u.w);
    }
    *(float4*)&xs[r][4 + seg * 8] = f0;
    *(float4*)&xs[r][8 + seg * 8] = f1;
  }
  if (tid < 36) {
    xs[tid][2] = 0.f; xs[tid][3] = 0.f; xs[tid][132] = 0.f; xs[tid][133] = 0.f;
  }
  __syncthreads();

  int pr = tid >> 5, pc = tid & 31;   // patch: rows ty0+pr*4.., cols pc*4..
  int px0 = pc * 4;
  int xrb = pr * 4;                   // xs row of first needed x-row (k=0)

  float acc[4][4];
#pragma unroll
  for (int r = 0; r < 4; ++r)
#pragma unroll
    for (int cc = 0; cc < 4; ++cc) acc[r][cc] = bias2;

  float X[3][8];
#define LOADROW(slot, rr)                                                     \
  {                                                                           \
    const float* xr = &xs[rr][px0 + 2];                                       \
    float2 aa = *(const float2*)xr;                                           \
    float4 bb = *(const float4*)(xr + 2);                                     \
    float2 cc2 = *(const float2*)(xr + 6);                                    \
    X[slot][0] = aa.x; X[slot][1] = aa.y;                                     \
    X[slot][2] = bb.x; X[slot][3] = bb.y; X[slot][4] = bb.z; X[slot][5] = bb.w;\
    X[slot][6] = cc2.x; X[slot][7] = cc2.y;                                   \
  }
  LOADROW(0, xrb)
  LOADROW(1, xrb + 1)

#pragma unroll
  for (int k = 0; k < 6; ++k) {
    LOADROW((k + 2) % 3, xrb + k + 2)
    bool rowok = (unsigned)(ty0 + pr * 4 - 1 + k) < 128u;
    float hA[6], hB[6];
#pragma unroll
    for (int j = 0; j < 6; ++j) {
      float sA = b1A, sB = b1B;
#pragma unroll
      for (int dy = 0; dy < 3; ++dy) {
        const float* xw = X[(k + dy) % 3];
#pragma unroll
        for (int dx = 0; dx < 3; ++dx) {
          float xv = xw[j + dx];
          sA = fmaf(xv, w1A[dy * 3 + dx], sA);
          sB = fmaf(xv, w1B[dy * 3 + dx], sB);
        }
      }
      // gelu: s/2 + s^2/sqrt(2pi) * (1 - u/6 + u^2/40), u=s^2, |s|<0.1
      float uA = sA * sA, uB = sB * sB;
      float tA = fmaf(uA, fmaf(uA, 0.025f, -0.16666667f), 1.0f);
      float tB = fmaf(uB, fmaf(uB, 0.025f, -0.16666667f), 1.0f);
      float gA = sA * fmaf(0.3989422804f * sA, tA, 0.5f);
      float gB = sB * fmaf(0.3989422804f * sB, tB, 0.5f);
      bool ok = rowok && ((unsigned)(px0 - 1 + j) < 128u);
      hA[j] = ok ? gA : 0.f;
      hB[j] = ok ? gB : 0.f;
    }
#pragma unroll
    for (int dy = 0; dy < 3; ++dy) {
      int r = k - dy;
      if (r >= 0 && r < 4) {
#pragma unroll
        for (int cc = 0; cc < 4; ++cc) {
          float a = acc[r][cc];
          a = fmaf(hA[cc],     w2A[dy * 3 + 0], a);
          a = fmaf(hA[cc + 1], w2A[dy * 3 + 1], a);
          a = fmaf(hA[cc + 2], w2A[dy * 3 + 2], a);
          a = fmaf(hB[cc],     w2B[dy * 3 + 0], a);
          a = fmaf(hB[cc + 1], w2B[dy * 3 + 1], a);
          a = fmaf(hB[cc + 2], w2B[dy * 3 + 2], a);
          acc[r][cc] = a;
        }
      }
    }
  }
#undef LOADROW

  float* op = out + ((size_t)b * C_OUT + c) * HW + (ty0 + pr * 4) * IMG + px0;
#pragma unroll
  for (int r = 0; r < 4; ++r)
    *(float4*)(op + r * IMG) = make_float4(acc[r][0], acc[r][1], acc[r][2], acc[r][3]);
}

extern "C" void kernel_launch(void* const* d_in, const int* in_sizes, int n_in,
                              void* d_out, int out_size, void* d_ws, size_t ws_size,
                              hipStream_t stream) {
  const float* x     = (const float*)d_in[0];
  const float* pre_w = (const float*)d_in[1];
  const float* pre_b = (const float*)d_in[2];
  const float* gw0   = (const float*)d_in[3];
  const float* gb0   = (const float*)d_in[4];
  const float* gw1   = (const float*)d_in[5];
  const float* gb1   = (const float*)d_in[6];
  const float* ew1   = (const float*)d_in[7];
  const float* eb1   = (const float*)d_in[8];
  const float* ew2   = (const float*)d_in[9];
  const float* eb2   = (const float*)d_in[10];
  float* out = (float*)d_out;

  char* ws = (char*)d_ws;
  unsigned short* x1 = (unsigned short*)ws;             // bf16, 16.78 MB
  float* pmax = (float*)(ws + 16777216);                // [512 strip][512 bo]
  float* psum = (float*)(ws + 17825792);
  float* cof  = (float*)(ws + 18874368);                // 32 fp32

  prefuse_mfma<<<4096, 64, 0, stream>>>(x, pre_w, pre_b, x1, pmax, psum);
  pool_gate_kernel<<<8, 256, 0, stream>>>(pmax, psum, gw0, gb0, gw1, gb1, cof);
  expert_kernel<<<2048, 256, 0, stream>>>(x1, ew1, eb1, ew2, eb2, cof, out);
}

// Round 14
// 70.822 us; speedup vs baseline: 1.3149x; 1.3149x over previous
//
#include <hip/hip_runtime.h>
#include <hip/hip_bf16.h>
#include <math.h>

#define HW 16384          // 128*128
#define IMG 128
#define C_IN 128
#define C_OUT 64
#define NB 8
#define NE 4

typedef __attribute__((ext_vector_type(8))) short bf16x8;
typedef __attribute__((ext_vector_type(4))) float f32x4;

static __device__ __forceinline__ float bf2f_u(unsigned hbits) {
  union { unsigned u; float f; } v; v.u = hbits << 16;
  return v.f;
}
static __device__ __forceinline__ float bf2f_hi(unsigned w) {
  union { unsigned u; float f; } v; v.u = w & 0xFFFF0000u;
  return v.f;
}
// HW packed conversion: two f32 -> one u32 of 2 bf16 (v_cvt_pk_bf16_f32)
static __device__ __forceinline__ unsigned cvtpk(float a, float b) {
  __hip_bfloat162 p = __float22bfloat162_rn(make_float2(a, b));
  union { __hip_bfloat162 h; unsigned u; } v; v.h = p;
  return v.u;
}
// Dekker split of a float pair
static __device__ __forceinline__ void pk2(float a, float b,
                                           unsigned& hi, unsigned& lo) {
  hi = cvtpk(a, b);
  float ra = a - bf2f_u(hi & 0xFFFFu);
  float rb = b - bf2f_u(hi >> 16);
  lo = cvtpk(ra, rb);
}

union FragU { unsigned u[4]; uint4 q; bf16x8 v; };

#define ASYNC_LOAD16(gsrc, ldst)                                              \
  __builtin_amdgcn_global_load_lds(                                           \
      (const __attribute__((address_space(1))) void*)(gsrc),                  \
      (__attribute__((address_space(3))) void*)(ldst), 16, 0, 0)

// ---- K1: pre-fuse 1x1 conv as MFMA GEMM, async-DMA X staging, inline W ----
__global__ __launch_bounds__(64, 4) void prefuse_mfma(
    const float* __restrict__ x, const float* __restrict__ pre_w,
    const float* __restrict__ pre_b, unsigned short* __restrict__ x1,
    float* __restrict__ pmax, float* __restrict__ psum) {
  __shared__ float xls[2][1024];            // 2 x 4KB k-step buffers
  __shared__ unsigned short tbuf[16][72];   // transpose buffer
  int lane = threadIdx.x;
  int rowb = lane & 15;                     // A-row(px) / B-col(o)
  int kg = lane >> 4;                       // k-group 0..3
  int blk = blockIdx.x;                     // 4096
  int b = blk >> 9;
  int strip = blk & 511;
  int px0 = strip << 5;                     // 32 px per strip

  const float* xbase = x + (size_t)b * C_IN * HW + px0;

#define STAGE(ks, bf)                                                         \
  {                                                                           \
    _Pragma("unroll")                                                         \
    for (int r = 0; r < 4; ++r) {                                             \
      int ch = (ks) * 32 + r * 8 + (lane >> 3);                               \
      int qs = (lane & 7) ^ ((r * 2 + (lane >> 5)) & 7);                      \
      ASYNC_LOAD16(xbase + (size_t)ch * HW + qs * 4, &xls[bf][r * 256]);      \
    }                                                                         \
  }

  STAGE(0, 0)

  f32x4 acc[2][4];                          // [px-tile][o-tile]
#pragma unroll
  for (int ot = 0; ot < 4; ++ot) {
    float t = pre_b[ot * 16 + rowb];
#pragma unroll
    for (int pt = 0; pt < 2; ++pt) acc[pt][ot] = (f32x4){t, t, t, t};
  }

#pragma unroll
  for (int k = 0; k < 4; ++k) {
    // inline W-frag pack for this k-step (block-redundant, measured free)
    FragU wh[4], wl[4];
#pragma unroll
    for (int ot = 0; ot < 4; ++ot) {
      const float* wp = pre_w + (ot * 16 + rowb) * C_IN + k * 32 + kg * 8;
      float4 a = *(const float4*)wp;
      float4 cq = *(const float4*)(wp + 4);
      pk2(a.x, a.y, wh[ot].u[0], wl[ot].u[0]);
      pk2(a.z, a.w, wh[ot].u[1], wl[ot].u[1]);
      pk2(cq.x, cq.y, wh[ot].u[2], wl[ot].u[2]);
      pk2(cq.z, cq.w, wh[ot].u[3], wl[ot].u[3]);
    }
    if (k < 3) {
      STAGE(k + 1, (k + 1) & 1)
      asm volatile("s_waitcnt vmcnt(4)" ::: "memory");  // buf k done; k+1 in flight
    } else {
      asm volatile("s_waitcnt vmcnt(0)" ::: "memory");
    }
    const float* xb = xls[k & 1];
#pragma unroll
    for (int pt = 0; pt < 2; ++pt) {
      float xv[8];
#pragma unroll
      for (int j = 0; j < 8; ++j) {
        int ch = kg * 8 + j;
        int qq = ((pt * 4 + (rowb >> 2)) ^ (ch >> 2)) & 7;
        xv[j] = xb[ch * 32 + qq * 4 + (rowb & 3)];
      }
      FragU h, l;
      pk2(xv[0], xv[1], h.u[0], l.u[0]);
      pk2(xv[2], xv[3], h.u[1], l.u[1]);
      pk2(xv[4], xv[5], h.u[2], l.u[2]);
      pk2(xv[6], xv[7], h.u[3], l.u[3]);
#pragma unroll
      for (int ot = 0; ot < 4; ++ot) {
        acc[pt][ot] = __builtin_amdgcn_mfma_f32_16x16x32_bf16(h.v, wh[ot].v, acc[pt][ot], 0, 0, 0);
        acc[pt][ot] = __builtin_amdgcn_mfma_f32_16x16x32_bf16(l.v, wh[ot].v, acc[pt][ot], 0, 0, 0);
        acc[pt][ot] = __builtin_amdgcn_mfma_f32_16x16x32_bf16(h.v, wl[ot].v, acc[pt][ot], 0, 0, 0);
      }
    }
  }
#undef STAGE

  // epilogue: pooling partials + LDS transpose -> bf16 x1 store
#pragma unroll
  for (int ot = 0; ot < 4; ++ot) {
    float m = -INFINITY, s = 0.f;
#pragma unroll
    for (int pt = 0; pt < 2; ++pt)
#pragma unroll
      for (int r = 0; r < 4; ++r) {
        float v = acc[pt][ot][r];
        m = fmaxf(m, v); s += v;
      }
    m = fmaxf(m, __shfl_xor(m, 16)); s += __shfl_xor(s, 16);
    m = fmaxf(m, __shfl_xor(m, 32)); s += __shfl_xor(s, 32);
    if (lane < 16) {
      int idx = strip * 512 + b * 64 + ot * 16 + lane;  // [strip][bo]
      pmax[idx] = m; psum[idx] = s;
    }
    // D: row(px) = pt*16 + kg*4 + r, col(o) = rowb
#pragma unroll
    for (int pt = 0; pt < 2; ++pt) {
      uint2 p;
      p.x = cvtpk(acc[pt][ot][0], acc[pt][ot][1]);
      p.y = cvtpk(acc[pt][ot][2], acc[pt][ot][3]);
      *(uint2*)&tbuf[rowb][pt * 16 + kg * 4] = p;
    }
    __syncthreads();  // 1-wave block: cheap ordering fence
    uint4 val = *(const uint4*)&tbuf[lane >> 2][(lane & 3) * 8];
    unsigned short* op = x1 + ((size_t)b * C_OUT + ot * 16 + (lane >> 2)) * HW
                            + px0 + (lane & 3) * 8;
    *(uint4*)op = val;
    __syncthreads();  // WAR guard before next ot reuses tbuf
  }
}

// ---- K2: finish pooling: one block per (b,o) ----
__global__ __launch_bounds__(64) void pool2_kernel(
    const float* __restrict__ pmax, const float* __restrict__ psum,
    float* __restrict__ pooled) {
  int bo = blockIdx.x;       // 0..511
  int lane = threadIdx.x;
  float m = -INFINITY, s = 0.f;
#pragma unroll
  for (int i = 0; i < 8; ++i) {
    int strip = lane + (i << 6);
    m = fmaxf(m, pmax[strip * 512 + bo]);
    s += psum[strip * 512 + bo];
  }
#pragma unroll
  for (int d = 32; d >= 1; d >>= 1) {
    m = fmaxf(m, __shfl_xor(m, d));
    s += __shfl_xor(s, d);
  }
  if (lane == 0) pooled[bo] = m + s * (1.0f / HW);
}

// ---- K3: gate network -> cof[B][E] ----
__global__ __launch_bounds__(64) void gate_kernel(
    const float* __restrict__ pooled, const float* __restrict__ gw0,
    const float* __restrict__ gb0, const float* __restrict__ gw1,
    const float* __restrict__ gb1, float* __restrict__ cof) {
  int b = threadIdx.x;
  if (b >= NB) return;
  float logits[NE], noise[NE];
#pragma unroll
  for (int e = 0; e < NE; ++e) {
    float d0 = gb0[e], d1 = gb1[e];
    for (int k = 0; k < C_OUT; ++k) {
      float pv = pooled[b * C_OUT + k];
      d0 = fmaf(pv, gw0[e * C_OUT + k], d0);
      d1 = fmaf(pv, gw1[e * C_OUT + k], d1);
    }
    logits[e] = d1 > 0.f ? d1 : 0.2f * d1;
    noise[e] = log1pf(expf(d0));
  }
  float mn = 0.25f * (noise[0] + noise[1] + noise[2] + noise[3]);
  float var = 0.f;
#pragma unroll
  for (int e = 0; e < NE; ++e) { float d = noise[e] - mn; var += d * d; }
  float sd = sqrtf(var * (1.0f / 3.0f));
  float scores[NE];
#pragma unroll
  for (int e = 0; e < NE; ++e) scores[e] = logits[e] + (noise[e] - mn) / sd;
  int i0 = 0;
#pragma unroll
  for (int e = 1; e < NE; ++e) if (scores[e] > scores[i0]) i0 = e;
  int i1 = -1;
#pragma unroll
  for (int e = 0; e < NE; ++e)
    if (e != i0 && (i1 < 0 || scores[e] > scores[i1])) i1 = e;
  float mm = fmaxf(logits[i0], logits[i1]);
  float e0 = expf(logits[i0] - mm), e1 = expf(logits[i1] - mm);
  float inv = 1.0f / (e0 + e1);
#pragma unroll
  for (int e = 0; e < NE; ++e) cof[b * NE + e] = 0.f;
  cof[b * NE + i0] = e0 * inv;
  cof[b * NE + i1] = e1 * inv;
}

// ---- K4: fused experts v2 — register-resident h, no hs LDS ----
// tile = 32 rows x 128 cols per (b,c); 256 threads, thread = 4x4 out patch.
__global__ __launch_bounds__(256) void expert_kernel(
    const unsigned short* __restrict__ x1, const float* __restrict__ ew1,
    const float* __restrict__ eb1, const float* __restrict__ ew2,
    const float* __restrict__ eb2, const float* __restrict__ cof,
    float* __restrict__ out) {
  __shared__ float xs[36][136];   // image col gx at 4+gx; halo cols 2,3,132,133
  int tid = threadIdx.x, blk = blockIdx.x;
  int rt = blk & 3;               // row tile 0..3
  int c = (blk >> 2) & 63;
  int b = blk >> 8;
  int ty0 = rt * 32;
  const unsigned short* xp = x1 + ((size_t)b * C_OUT + c) * HW;

  // the two active experts (uniform per block)
  int eA = -1, eB = -1; float cfA = 0.f, cfB = 0.f;
#pragma unroll
  for (int e = 0; e < NE; ++e) {
    float cv = cof[b * NE + e];
    if (cv != 0.f) { if (eA < 0) { eA = e; cfA = cv; } else { eB = e; cfB = cv; } }
  }
  if (eA < 0) { eA = 0; cfA = 0.f; }
  if (eB < 0) { eB = eA; cfB = 0.f; }

  float w1A[9], w1B[9], w2A[9], w2B[9];
#pragma unroll
  for (int t = 0; t < 9; ++t) {
    w1A[t] = ew1[((size_t)eA * C_OUT + c) * 9 + t];
    w1B[t] = ew1[((size_t)eB * C_OUT + c) * 9 + t];
    w2A[t] = cfA * ew2[((size_t)eA * C_OUT + c) * 9 + t];
    w2B[t] = cfB * ew2[((size_t)eB * C_OUT + c) * 9 + t];
  }
  float b1A = eb1[eA * C_OUT + c], b1B = eb1[eB * C_OUT + c];
  float bias2 = cfA * eb2[eA * C_OUT + c] + cfB * eb2[eB * C_OUT + c];

  // stage 36 rows x 128 cols (bf16 -> fp32), zeros outside image
  for (int i = tid; i < 36 * 16; i += 256) {
    int r = i >> 4, seg = i & 15;
    int gy = ty0 - 2 + r;
    float4 f0 = make_float4(0.f, 0.f, 0.f, 0.f), f1 = f0;
    if ((unsigned)gy < 128u) {
      uint4 u = *(const uint4*)(xp + gy * IMG + seg * 8);
      f0.x = bf2f_u(u.x); f0.y = bf2f_hi(u.x);
      f0.z = bf2f_u(u.y); f0.w = bf2f_hi(u.y);
      f1.x = bf2f_u(u.z); f1.y = bf2f_hi(u.z);
      f1.z = bf2f_u(u.w); f1.w = bf2f_hi(u.w);
    }
    *(float4*)&xs[r][4 + seg * 8] = f0;
    *(float4*)&xs[r][8 + seg * 8] = f1;
  }
  if (tid < 36) {
    xs[tid][2] = 0.f; xs[tid][3] = 0.f; xs[tid][132] = 0.f; xs[tid][133] = 0.f;
  }
  __syncthreads();

  int pr = tid >> 5, pc = tid & 31;   // patch: rows ty0+pr*4.., cols pc*4..
  int px0 = pc * 4;
  int xrb = pr * 4;                   // xs row of first needed x-row (k=0)

  float acc[4][4];
#pragma unroll
  for (int r = 0; r < 4; ++r)
#pragma unroll
    for (int cc = 0; cc < 4; ++cc) acc[r][cc] = bias2;

  float X[3][8];
#define LOADROW(slot, rr)                                                     \
  {                                                                           \
    const float* xr = &xs[rr][px0 + 2];                                       \
    float2 aa = *(const float2*)xr;                                           \
    float4 bb = *(const float4*)(xr + 2);                                     \
    float2 cc2 = *(const float2*)(xr + 6);                                    \
    X[slot][0] = aa.x; X[slot][1] = aa.y;                                     \
    X[slot][2] = bb.x; X[slot][3] = bb.y; X[slot][4] = bb.z; X[slot][5] = bb.w;\
    X[slot][6] = cc2.x; X[slot][7] = cc2.y;                                   \
  }
  LOADROW(0, xrb)
  LOADROW(1, xrb + 1)

#pragma unroll
  for (int k = 0; k < 6; ++k) {
    LOADROW((k + 2) % 3, xrb + k + 2)
    bool rowok = (unsigned)(ty0 + pr * 4 - 1 + k) < 128u;
    float hA[6], hB[6];
#pragma unroll
    for (int j = 0; j < 6; ++j) {
      float sA = b1A, sB = b1B;
#pragma unroll
      for (int dy = 0; dy < 3; ++dy) {
        const float* xw = X[(k + dy) % 3];
#pragma unroll
        for (int dx = 0; dx < 3; ++dx) {
          float xv = xw[j + dx];
          sA = fmaf(xv, w1A[dy * 3 + dx], sA);
          sB = fmaf(xv, w1B[dy * 3 + dx], sB);
        }
      }
      // gelu: s/2 + s^2/sqrt(2pi) * (1 - u/6 + u^2/40), u=s^2, |s|<0.1
      float uA = sA * sA, uB = sB * sB;
      float tA = fmaf(uA, fmaf(uA, 0.025f, -0.16666667f), 1.0f);
      float tB = fmaf(uB, fmaf(uB, 0.025f, -0.16666667f), 1.0f);
      float gA = sA * fmaf(0.3989422804f * sA, tA, 0.5f);
      float gB = sB * fmaf(0.3989422804f * sB, tB, 0.5f);
      bool ok = rowok && ((unsigned)(px0 - 1 + j) < 128u);
      hA[j] = ok ? gA : 0.f;
      hB[j] = ok ? gB : 0.f;
    }
#pragma unroll
    for (int dy = 0; dy < 3; ++dy) {
      int r = k - dy;
      if (r >= 0 && r < 4) {
#pragma unroll
        for (int cc = 0; cc < 4; ++cc) {
          float a = acc[r][cc];
          a = fmaf(hA[cc],     w2A[dy * 3 + 0], a);
          a = fmaf(hA[cc + 1], w2A[dy * 3 + 1], a);
          a = fmaf(hA[cc + 2], w2A[dy * 3 + 2], a);
          a = fmaf(hB[cc],     w2B[dy * 3 + 0], a);
          a = fmaf(hB[cc + 1], w2B[dy * 3 + 1], a);
          a = fmaf(hB[cc + 2], w2B[dy * 3 + 2], a);
          acc[r][cc] = a;
        }
      }
    }
  }
#undef LOADROW

  float* op = out + ((size_t)b * C_OUT + c) * HW + (ty0 + pr * 4) * IMG + px0;
#pragma unroll
  for (int r = 0; r < 4; ++r)
    *(float4*)(op + r * IMG) = make_float4(acc[r][0], acc[r][1], acc[r][2], acc[r][3]);
}

extern "C" void kernel_launch(void* const* d_in, const int* in_sizes, int n_in,
                              void* d_out, int out_size, void* d_ws, size_t ws_size,
                              hipStream_t stream) {
  const float* x     = (const float*)d_in[0];
  const float* pre_w = (const float*)d_in[1];
  const float* pre_b = (const float*)d_in[2];
  const float* gw0   = (const float*)d_in[3];
  const float* gb0   = (const float*)d_in[4];
  const float* gw1   = (const float*)d_in[5];
  const float* gb1   = (const float*)d_in[6];
  const float* ew1   = (const float*)d_in[7];
  const float* eb1   = (const float*)d_in[8];
  const float* ew2   = (const float*)d_in[9];
  const float* eb2   = (const float*)d_in[10];
  float* out = (float*)d_out;

  char* ws = (char*)d_ws;
  unsigned short* x1 = (unsigned short*)ws;             // bf16, 16.78 MB
  float* pmax   = (float*)(ws + 16777216);              // [512 strip][512 bo]
  float* psum   = (float*)(ws + 17825792);
  float* pooled = (float*)(ws + 18874368);              // 512 fp32
  float* cof    = (float*)(ws + 18876416);              // 32 fp32

  prefuse_mfma<<<4096, 64, 0, stream>>>(x, pre_w, pre_b, x1, pmax, psum);
  pool2_kernel<<<512, 64, 0, stream>>>(pmax, psum, pooled);
  gate_kernel<<<1, 64, 0, stream>>>(pooled, gw0, gb0, gw1, gb1, cof);
  expert_kernel<<<2048, 256, 0, stream>>>(x1, ew1, eb1, ew2, eb2, cof, out);
}

// Round 15
// 68.040 us; speedup vs baseline: 1.3686x; 1.0409x over previous
//
#include <hip/hip_runtime.h>
#include <hip/hip_bf16.h>
#include <math.h>

#define HW 16384          // 128*128
#define IMG 128
#define C_IN 128
#define C_OUT 64
#define NB 8
#define NE 4

typedef __attribute__((ext_vector_type(8))) short bf16x8;
typedef __attribute__((ext_vector_type(4))) float f32x4;

static __device__ __forceinline__ float bf2f_u(unsigned hbits) {
  union { unsigned u; float f; } v; v.u = hbits << 16;
  return v.f;
}
static __device__ __forceinline__ float bf2f_hi(unsigned w) {
  union { unsigned u; float f; } v; v.u = w & 0xFFFF0000u;
  return v.f;
}
// HW packed conversion: two f32 -> one u32 of 2 bf16 (v_cvt_pk_bf16_f32)
static __device__ __forceinline__ unsigned cvtpk(float a, float b) {
  __hip_bfloat162 p = __float22bfloat162_rn(make_float2(a, b));
  union { __hip_bfloat162 h; unsigned u; } v; v.h = p;
  return v.u;
}
// Dekker split of a float pair
static __device__ __forceinline__ void pk2(float a, float b,
                                           unsigned& hi, unsigned& lo) {
  hi = cvtpk(a, b);
  float ra = a - bf2f_u(hi & 0xFFFFu);
  float rb = b - bf2f_u(hi >> 16);
  lo = cvtpk(ra, rb);
}

union FragU { unsigned u[4]; uint4 q; bf16x8 v; };

#define ASYNC_LOAD16(gsrc, ldst)                                              \
  __builtin_amdgcn_global_load_lds(                                           \
      (const __attribute__((address_space(1))) void*)(gsrc),                  \
      (__attribute__((address_space(3))) void*)(ldst), 16, 0, 0)

// ---- K1: pre-fuse 1x1 conv as MFMA GEMM, async-DMA X staging, inline W ----
__global__ __launch_bounds__(64, 4) void prefuse_mfma(
    const float* __restrict__ x, const float* __restrict__ pre_w,
    const float* __restrict__ pre_b, unsigned short* __restrict__ x1,
    float* __restrict__ pmax, float* __restrict__ psum) {
  __shared__ float xls[2][1024];            // 2 x 4KB k-step buffers
  __shared__ unsigned short tbuf[16][72];   // transpose buffer
  int lane = threadIdx.x;
  int rowb = lane & 15;                     // A-row(px) / B-col(o)
  int kg = lane >> 4;                       // k-group 0..3
  int blk = blockIdx.x;                     // 4096
  int b = blk >> 9;
  int strip = blk & 511;
  int px0 = strip << 5;                     // 32 px per strip

  const float* xbase = x + (size_t)b * C_IN * HW + px0;

#define STAGE(ks, bf)                                                         \
  {                                                                           \
    _Pragma("unroll")                                                         \
    for (int r = 0; r < 4; ++r) {                                             \
      int ch = (ks) * 32 + r * 8 + (lane >> 3);                               \
      int qs = (lane & 7) ^ ((r * 2 + (lane >> 5)) & 7);                      \
      ASYNC_LOAD16(xbase + (size_t)ch * HW + qs * 4, &xls[bf][r * 256]);      \
    }                                                                         \
  }

  STAGE(0, 0)

  f32x4 acc[2][4];                          // [px-tile][o-tile]
#pragma unroll
  for (int ot = 0; ot < 4; ++ot) {
    float t = pre_b[ot * 16 + rowb];
#pragma unroll
    for (int pt = 0; pt < 2; ++pt) acc[pt][ot] = (f32x4){t, t, t, t};
  }

#pragma unroll
  for (int k = 0; k < 4; ++k) {
    // inline W-frag pack for this k-step (block-redundant, measured free)
    FragU wh[4], wl[4];
#pragma unroll
    for (int ot = 0; ot < 4; ++ot) {
      const float* wp = pre_w + (ot * 16 + rowb) * C_IN + k * 32 + kg * 8;
      float4 a = *(const float4*)wp;
      float4 cq = *(const float4*)(wp + 4);
      pk2(a.x, a.y, wh[ot].u[0], wl[ot].u[0]);
      pk2(a.z, a.w, wh[ot].u[1], wl[ot].u[1]);
      pk2(cq.x, cq.y, wh[ot].u[2], wl[ot].u[2]);
      pk2(cq.z, cq.w, wh[ot].u[3], wl[ot].u[3]);
    }
    if (k < 3) {
      STAGE(k + 1, (k + 1) & 1)
      asm volatile("s_waitcnt vmcnt(4)" ::: "memory");  // buf k done; k+1 in flight
    } else {
      asm volatile("s_waitcnt vmcnt(0)" ::: "memory");
    }
    const float* xb = xls[k & 1];
#pragma unroll
    for (int pt = 0; pt < 2; ++pt) {
      float xv[8];
#pragma unroll
      for (int j = 0; j < 8; ++j) {
        int ch = kg * 8 + j;
        int qq = ((pt * 4 + (rowb >> 2)) ^ (ch >> 2)) & 7;
        xv[j] = xb[ch * 32 + qq * 4 + (rowb & 3)];
      }
      FragU h, l;
      pk2(xv[0], xv[1], h.u[0], l.u[0]);
      pk2(xv[2], xv[3], h.u[1], l.u[1]);
      pk2(xv[4], xv[5], h.u[2], l.u[2]);
      pk2(xv[6], xv[7], h.u[3], l.u[3]);
#pragma unroll
      for (int ot = 0; ot < 4; ++ot) {
        acc[pt][ot] = __builtin_amdgcn_mfma_f32_16x16x32_bf16(h.v, wh[ot].v, acc[pt][ot], 0, 0, 0);
        acc[pt][ot] = __builtin_amdgcn_mfma_f32_16x16x32_bf16(l.v, wh[ot].v, acc[pt][ot], 0, 0, 0);
        acc[pt][ot] = __builtin_amdgcn_mfma_f32_16x16x32_bf16(h.v, wl[ot].v, acc[pt][ot], 0, 0, 0);
      }
    }
  }
#undef STAGE

  // epilogue: pooling partials + LDS transpose -> bf16 x1 store
#pragma unroll
  for (int ot = 0; ot < 4; ++ot) {
    float m = -INFINITY, s = 0.f;
#pragma unroll
    for (int pt = 0; pt < 2; ++pt)
#pragma unroll
      for (int r = 0; r < 4; ++r) {
        float v = acc[pt][ot][r];
        m = fmaxf(m, v); s += v;
      }
    m = fmaxf(m, __shfl_xor(m, 16)); s += __shfl_xor(s, 16);
    m = fmaxf(m, __shfl_xor(m, 32)); s += __shfl_xor(s, 32);
    if (lane < 16) {
      int idx = strip * 512 + b * 64 + ot * 16 + lane;  // [strip][bo]
      pmax[idx] = m; psum[idx] = s;
    }
    // D: row(px) = pt*16 + kg*4 + r, col(o) = rowb
#pragma unroll
    for (int pt = 0; pt < 2; ++pt) {
      uint2 p;
      p.x = cvtpk(acc[pt][ot][0], acc[pt][ot][1]);
      p.y = cvtpk(acc[pt][ot][2], acc[pt][ot][3]);
      *(uint2*)&tbuf[rowb][pt * 16 + kg * 4] = p;
    }
    __syncthreads();  // 1-wave block: cheap ordering fence
    uint4 val = *(const uint4*)&tbuf[lane >> 2][(lane & 3) * 8];
    unsigned short* op = x1 + ((size_t)b * C_OUT + ot * 16 + (lane >> 2)) * HW
                            + px0 + (lane & 3) * 8;
    *(uint4*)op = val;
    __syncthreads();  // WAR guard before next ot reuses tbuf
  }
}

// ---- K2: finish pooling: one block per (b,o) ----
__global__ __launch_bounds__(64) void pool2_kernel(
    const float* __restrict__ pmax, const float* __restrict__ psum,
    float* __restrict__ pooled) {
  int bo = blockIdx.x;       // 0..511
  int lane = threadIdx.x;
  float m = -INFINITY, s = 0.f;
#pragma unroll
  for (int i = 0; i < 8; ++i) {
    int strip = lane + (i << 6);
    m = fmaxf(m, pmax[strip * 512 + bo]);
    s += psum[strip * 512 + bo];
  }
#pragma unroll
  for (int d = 32; d >= 1; d >>= 1) {
    m = fmaxf(m, __shfl_xor(m, d));
    s += __shfl_xor(s, d);
  }
  if (lane == 0) pooled[bo] = m + s * (1.0f / HW);
}

// ---- K3: gate network v2 — wave-parallel dot products ----
// 8 waves, wave b = batch b; lane k holds pooled[b*64+k]; butterfly reduce
// all 8 partial dots (4 experts x {noise, logit}) simultaneously.
__global__ __launch_bounds__(512) void gate_kernel(
    const float* __restrict__ pooled, const float* __restrict__ gw0,
    const float* __restrict__ gb0, const float* __restrict__ gw1,
    const float* __restrict__ gb1, float* __restrict__ cof) {
  int b = threadIdx.x >> 6, lane = threadIdx.x & 63;
  float pv = pooled[b * C_OUT + lane];
  float acc[8];
#pragma unroll
  for (int e = 0; e < NE; ++e) {
    acc[e]      = pv * gw0[e * C_OUT + lane];
    acc[4 + e]  = pv * gw1[e * C_OUT + lane];
  }
#pragma unroll
  for (int d = 32; d >= 1; d >>= 1)
#pragma unroll
    for (int q = 0; q < 8; ++q) acc[q] += __shfl_xor(acc[q], d);

  if (lane == 0) {
    float logits[NE], noise[NE];
#pragma unroll
    for (int e = 0; e < NE; ++e) {
      float d0 = acc[e] + gb0[e];
      float d1 = acc[4 + e] + gb1[e];
      logits[e] = d1 > 0.f ? d1 : 0.2f * d1;      // leaky_relu(0.2)
      noise[e] = log1pf(expf(d0));                 // softplus
    }
    float mn = 0.25f * (noise[0] + noise[1] + noise[2] + noise[3]);
    float var = 0.f;
#pragma unroll
    for (int e = 0; e < NE; ++e) { float d = noise[e] - mn; var += d * d; }
    float sd = sqrtf(var * (1.0f / 3.0f));         // ddof=1
    float scores[NE];
#pragma unroll
    for (int e = 0; e < NE; ++e) scores[e] = logits[e] + (noise[e] - mn) / sd;
    int i0 = 0;
#pragma unroll
    for (int e = 1; e < NE; ++e) if (scores[e] > scores[i0]) i0 = e;
    int i1 = -1;
#pragma unroll
    for (int e = 0; e < NE; ++e)
      if (e != i0 && (i1 < 0 || scores[e] > scores[i1])) i1 = e;
    float mm = fmaxf(logits[i0], logits[i1]);
    float e0 = expf(logits[i0] - mm), e1 = expf(logits[i1] - mm);
    float inv = 1.0f / (e0 + e1);
#pragma unroll
    for (int e = 0; e < NE; ++e) cof[b * NE + e] = 0.f;
    cof[b * NE + i0] = e0 * inv;
    cof[b * NE + i1] = e1 * inv;
  }
}

// ---- K4: fused experts v2 — register-resident h, no hs LDS ----
// tile = 32 rows x 128 cols per (b,c); 256 threads, thread = 4x4 out patch.
__global__ __launch_bounds__(256) void expert_kernel(
    const unsigned short* __restrict__ x1, const float* __restrict__ ew1,
    const float* __restrict__ eb1, const float* __restrict__ ew2,
    const float* __restrict__ eb2, const float* __restrict__ cof,
    float* __restrict__ out) {
  __shared__ float xs[36][136];   // image col gx at 4+gx; halo cols 2,3,132,133
  int tid = threadIdx.x, blk = blockIdx.x;
  int rt = blk & 3;               // row tile 0..3
  int c = (blk >> 2) & 63;
  int b = blk >> 8;
  int ty0 = rt * 32;
  const unsigned short* xp = x1 + ((size_t)b * C_OUT + c) * HW;

  // the two active experts (uniform per block)
  int eA = -1, eB = -1; float cfA = 0.f, cfB = 0.f;
#pragma unroll
  for (int e = 0; e < NE; ++e) {
    float cv = cof[b * NE + e];
    if (cv != 0.f) { if (eA < 0) { eA = e; cfA = cv; } else { eB = e; cfB = cv; } }
  }
  if (eA < 0) { eA = 0; cfA = 0.f; }
  if (eB < 0) { eB = eA; cfB = 0.f; }

  float w1A[9], w1B[9], w2A[9], w2B[9];
#pragma unroll
  for (int t = 0; t < 9; ++t) {
    w1A[t] = ew1[((size_t)eA * C_OUT + c) * 9 + t];
    w1B[t] = ew1[((size_t)eB * C_OUT + c) * 9 + t];
    w2A[t] = cfA * ew2[((size_t)eA * C_OUT + c) * 9 + t];
    w2B[t] = cfB * ew2[((size_t)eB * C_OUT + c) * 9 + t];
  }
  float b1A = eb1[eA * C_OUT + c], b1B = eb1[eB * C_OUT + c];
  float bias2 = cfA * eb2[eA * C_OUT + c] + cfB * eb2[eB * C_OUT + c];

  // stage 36 rows x 128 cols (bf16 -> fp32), zeros outside image
  for (int i = tid; i < 36 * 16; i += 256) {
    int r = i >> 4, seg = i & 15;
    int gy = ty0 - 2 + r;
    float4 f0 = make_float4(0.f, 0.f, 0.f, 0.f), f1 = f0;
    if ((unsigned)gy < 128u) {
      uint4 u = *(const uint4*)(xp + gy * IMG + seg * 8);
      f0.x = bf2f_u(u.x); f0.y = bf2f_hi(u.x);
      f0.z = bf2f_u(u.y); f0.w = bf2f_hi(u.y);
      f1.x = bf2f_u(u.z); f1.y = bf2f_hi(u.z);
      f1.z = bf2f_u(u.w); f1.w = bf2f_hi(u.w);
    }
    *(float4*)&xs[r][4 + seg * 8] = f0;
    *(float4*)&xs[r][8 + seg * 8] = f1;
  }
  if (tid < 36) {
    xs[tid][2] = 0.f; xs[tid][3] = 0.f; xs[tid][132] = 0.f; xs[tid][133] = 0.f;
  }
  __syncthreads();

  int pr = tid >> 5, pc = tid & 31;   // patch: rows ty0+pr*4.., cols pc*4..
  int px0 = pc * 4;
  int xrb = pr * 4;                   // xs row of first needed x-row (k=0)

  float acc[4][4];
#pragma unroll
  for (int r = 0; r < 4; ++r)
#pragma unroll
    for (int cc = 0; cc < 4; ++cc) acc[r][cc] = bias2;

  float X[3][8];
#define LOADROW(slot, rr)                                                     \
  {                                                                           \
    const float* xr = &xs[rr][px0 + 2];                                       \
    float2 aa = *(const float2*)xr;                                           \
    float4 bb = *(const float4*)(xr + 2);                                     \
    float2 cc2 = *(const float2*)(xr + 6);                                    \
    X[slot][0] = aa.x; X[slot][1] = aa.y;                                     \
    X[slot][2] = bb.x; X[slot][3] = bb.y; X[slot][4] = bb.z; X[slot][5] = bb.w;\
    X[slot][6] = cc2.x; X[slot][7] = cc2.y;                                   \
  }
  LOADROW(0, xrb)
  LOADROW(1, xrb + 1)

#pragma unroll
  for (int k = 0; k < 6; ++k) {
    LOADROW((k + 2) % 3, xrb + k + 2)
    bool rowok = (unsigned)(ty0 + pr * 4 - 1 + k) < 128u;
    float hA[6], hB[6];
#pragma unroll
    for (int j = 0; j < 6; ++j) {
      float sA = b1A, sB = b1B;
#pragma unroll
      for (int dy = 0; dy < 3; ++dy) {
        const float* xw = X[(k + dy) % 3];
#pragma unroll
        for (int dx = 0; dx < 3; ++dx) {
          float xv = xw[j + dx];
          sA = fmaf(xv, w1A[dy * 3 + dx], sA);
          sB = fmaf(xv, w1B[dy * 3 + dx], sB);
        }
      }
      // gelu: s/2 + s^2/sqrt(2pi) * (1 - u/6 + u^2/40), u=s^2, |s|<0.1
      float uA = sA * sA, uB = sB * sB;
      float tA = fmaf(uA, fmaf(uA, 0.025f, -0.16666667f), 1.0f);
      float tB = fmaf(uB, fmaf(uB, 0.025f, -0.16666667f), 1.0f);
      float gA = sA * fmaf(0.3989422804f * sA, tA, 0.5f);
      float gB = sB * fmaf(0.3989422804f * sB, tB, 0.5f);
      bool ok = rowok && ((unsigned)(px0 - 1 + j) < 128u);
      hA[j] = ok ? gA : 0.f;
      hB[j] = ok ? gB : 0.f;
    }
#pragma unroll
    for (int dy = 0; dy < 3; ++dy) {
      int r = k - dy;
      if (r >= 0 && r < 4) {
#pragma unroll
        for (int cc = 0; cc < 4; ++cc) {
          float a = acc[r][cc];
          a = fmaf(hA[cc],     w2A[dy * 3 + 0], a);
          a = fmaf(hA[cc + 1], w2A[dy * 3 + 1], a);
          a = fmaf(hA[cc + 2], w2A[dy * 3 + 2], a);
          a = fmaf(hB[cc],     w2B[dy * 3 + 0], a);
          a = fmaf(hB[cc + 1], w2B[dy * 3 + 1], a);
          a = fmaf(hB[cc + 2], w2B[dy * 3 + 2], a);
          acc[r][cc] = a;
        }
      }
    }
  }
#undef LOADROW

  float* op = out + ((size_t)b * C_OUT + c) * HW + (ty0 + pr * 4) * IMG + px0;
#pragma unroll
  for (int r = 0; r < 4; ++r)
    *(float4*)(op + r * IMG) = make_float4(acc[r][0], acc[r][1], acc[r][2], acc[r][3]);
}

extern "C" void kernel_launch(void* const* d_in, const int* in_sizes, int n_in,
                              void* d_out, int out_size, void* d_ws, size_t ws_size,
                              hipStream_t stream) {
  const float* x     = (const float*)d_in[0];
  const float* pre_w = (const float*)d_in[1];
  const float* pre_b = (const float*)d_in[2];
  const float* gw0   = (const float*)d_in[3];
  const float* gb0   = (const float*)d_in[4];
  const float* gw1   = (const float*)d_in[5];
  const float* gb1   = (const float*)d_in[6];
  const float* ew1   = (const float*)d_in[7];
  const float* eb1   = (const float*)d_in[8];
  const float* ew2   = (const float*)d_in[9];
  const float* eb2   = (const float*)d_in[10];
  float* out = (float*)d_out;

  char* ws = (char*)d_ws;
  unsigned short* x1 = (unsigned short*)ws;             // bf16, 16.78 MB
  float* pmax   = (float*)(ws + 16777216);              // [512 strip][512 bo]
  float* psum   = (float*)(ws + 17825792);
  float* pooled = (float*)(ws + 18874368);              // 512 fp32
  float* cof    = (float*)(ws + 18876416);              // 32 fp32

  prefuse_mfma<<<4096, 64, 0, stream>>>(x, pre_w, pre_b, x1, pmax, psum);
  pool2_kernel<<<512, 64, 0, stream>>>(pmax, psum, pooled);
  gate_kernel<<<1, 512, 0, stream>>>(pooled, gw0, gb0, gw1, gb1, cof);
  expert_kernel<<<2048, 256, 0, stream>>>(x1, ew1, eb1, ew2, eb2, cof, out);
}